// Round 2
// baseline (8768.566 us; speedup 1.0000x reference)
//
#include <hip/hip_runtime.h>

#define NN 50000
#define FF 128
#define UU 128
#define NREL 8
#define NE 60000

__device__ __forceinline__ void fma4(float* ar, float s, const float4& wv) {
    ar[0] = fmaf(s, wv.x, ar[0]);
    ar[1] = fmaf(s, wv.y, ar[1]);
    ar[2] = fmaf(s, wv.z, ar[2]);
    ar[3] = fmaf(s, wv.w, ar[3]);
}

// Y[N,128] = X[N,128] @ W[128,128] (+bias). Tile: 64 rows x 128 cols per
// 256-thread block; each thread: 8 rows x 4 cols. X tile staged in LDS,
// W read through L1/L2 (64KB, hot across all blocks).
__global__ __launch_bounds__(256, 2) void gemm_kernel(
    const float* __restrict__ X, const float* __restrict__ W,
    const float* __restrict__ bias, float* __restrict__ Y, int n_rows)
{
    __shared__ float xs[64 * FF];
    const int t = threadIdx.x;
    const int row0 = blockIdx.x * 64;

    // stage x tile: 64 rows * 128 cols = 2048 float4, 8 per thread, coalesced
    const float4* xt = (const float4*)(X + (size_t)row0 * FF);
    float4* xs4 = (float4*)xs;
    const int lim = (n_rows - row0) * (FF / 4);
    #pragma unroll
    for (int j = 0; j < 8; ++j) {
        int idx = t + j * 256;
        float4 v = make_float4(0.f, 0.f, 0.f, 0.f);
        if (idx < lim) v = xt[idx];
        xs4[idx] = v;
    }
    __syncthreads();

    const int tx = t & 31;   // col group: cols 4*tx .. 4*tx+3
    const int ty = t >> 5;   // row group: rows 8*ty .. 8*ty+7

    float acc[8][4];
    #pragma unroll
    for (int r = 0; r < 8; ++r)
        #pragma unroll
        for (int c = 0; c < 4; ++c) acc[r][c] = 0.f;

    #pragma unroll
    for (int k0 = 0; k0 < FF; k0 += 4) {
        float4 xv[8];
        #pragma unroll
        for (int r = 0; r < 8; ++r)
            xv[r] = *(const float4*)&xs[(8 * ty + r) * FF + k0];
        float4 w0 = *(const float4*)&W[(size_t)(k0 + 0) * UU + 4 * tx];
        float4 w1 = *(const float4*)&W[(size_t)(k0 + 1) * UU + 4 * tx];
        float4 w2 = *(const float4*)&W[(size_t)(k0 + 2) * UU + 4 * tx];
        float4 w3 = *(const float4*)&W[(size_t)(k0 + 3) * UU + 4 * tx];
        #pragma unroll
        for (int r = 0; r < 8; ++r) {
            fma4(acc[r], xv[r].x, w0);
            fma4(acc[r], xv[r].y, w1);
            fma4(acc[r], xv[r].z, w2);
            fma4(acc[r], xv[r].w, w3);
        }
    }

    float4 bv = make_float4(0.f, 0.f, 0.f, 0.f);
    if (bias) bv = *(const float4*)&bias[4 * tx];
    #pragma unroll
    for (int r = 0; r < 8; ++r) {
        int row = row0 + 8 * ty + r;
        if (row < n_rows) {
            float4 o = make_float4(acc[r][0] + bv.x, acc[r][1] + bv.y,
                                   acc[r][2] + bv.z, acc[r][3] + bv.w);
            *(float4*)&Y[(size_t)row * UU + 4 * tx] = o;
        }
    }
}

// One wave (64 lanes) per edge: gather hr[src], scale by w, atomicAdd into out[dst].
__global__ __launch_bounds__(256, 8) void scatter_kernel(
    const float* __restrict__ hr, const int* __restrict__ src,
    const int* __restrict__ dst, const float* __restrict__ w,
    float* __restrict__ out, int n_edges)
{
    int gid = blockIdx.x * (256 >> 6) + (threadIdx.x >> 6);
    int lane = threadIdx.x & 63;
    if (gid >= n_edges) return;
    int s = src[gid];
    int d = dst[gid];
    float we = w[gid];
    const float2 v = ((const float2*)(hr + (size_t)s * UU))[lane];
    float* orow = out + (size_t)d * UU;
    atomicAdd(&orow[2 * lane + 0], v.x * we);
    atomicAdd(&orow[2 * lane + 1], v.y * we);
}

__global__ __launch_bounds__(256, 8) void relu_kernel(float* __restrict__ y, int n4)
{
    int i = blockIdx.x * 256 + threadIdx.x;
    if (i < n4) {
        float4 v = ((float4*)y)[i];
        v.x = fmaxf(v.x, 0.f);
        v.y = fmaxf(v.y, 0.f);
        v.z = fmaxf(v.z, 0.f);
        v.w = fmaxf(v.w, 0.f);
        ((float4*)y)[i] = v;
    }
}

extern "C" void kernel_launch(void* const* d_in, const int* in_sizes, int n_in,
                              void* d_out, int out_size, void* d_ws, size_t ws_size,
                              hipStream_t stream) {
    const float* X     = (const float*)d_in[0];  // [1,50000,128]
    const int*   esrc  = (const int*)d_in[1];    // [8,60000]
    const int*   edst  = (const int*)d_in[2];    // [8,60000]
    const float* ew    = (const float*)d_in[3];  // [8,60000]
    const float* Wself = (const float*)d_in[4];  // [128,128]
    const float* Wrel  = (const float*)d_in[5];  // [8,128,128]
    const float* bias  = (const float*)d_in[6];  // [128]
    float* out = (float*)d_out;                  // [1,50000,128] fp32, used as accumulator
    float* hr  = (float*)d_ws;                   // [50000,128] fp32 scratch (25.6MB)

    const int gemm_grid = (NN + 63) / 64;        // 782
    const int scat_grid = (NE + 3) / 4;          // 15000 (4 waves/block, 1 edge/wave)

    // out = X @ Wself + bias
    hipLaunchKernelGGL(gemm_kernel, dim3(gemm_grid), dim3(256), 0, stream,
                       X, Wself, bias, out, NN);

    // per relation: hr = X @ Wr; out[dst] += w * hr[src]
    for (int r = 0; r < NREL; ++r) {
        hipLaunchKernelGGL(gemm_kernel, dim3(gemm_grid), dim3(256), 0, stream,
                           X, Wrel + (size_t)r * FF * UU, (const float*)nullptr, hr, NN);
        hipLaunchKernelGGL(scatter_kernel, dim3(scat_grid), dim3(256), 0, stream,
                           hr, esrc + r * NE, edst + r * NE, ew + r * NE, out, NE);
    }

    // out = relu(out), in place (out is fully rewritten by the first kernel
    // every call, so this is replay-safe)
    hipLaunchKernelGGL(relu_kernel, dim3((NN * UU / 4 + 255) / 256), dim3(256), 0, stream,
                       out, NN * UU / 4);
}

// Round 3
// 630.763 us; speedup vs baseline: 13.9015x; 13.9015x over previous
//
#include <hip/hip_runtime.h>

#define NN 50000
#define FF 128
#define UU 128
#define NREL 8
#define NE 60000

// ---- shared tile compute: Y[row0..row0+63, :] = xs(64x128) @ W(128x128) + bv
// SROA-safe: float4 accumulators, static indices only, no escaping pointers.
__device__ __forceinline__ void gemm_tile_compute(
    const float* xs, const float* __restrict__ W, float4 bv,
    float* __restrict__ Y, int row0, int n_rows, int tx, int ty)
{
    float4 acc[8];
    #pragma unroll
    for (int r = 0; r < 8; ++r) acc[r] = make_float4(0.f, 0.f, 0.f, 0.f);

    const float4* Wc = (const float4*)W + tx;   // row k of W, cols 4*tx..4*tx+3 = Wc[k*32]

    #pragma unroll 2
    for (int k0 = 0; k0 < FF; k0 += 4) {
        float4 w0 = Wc[(k0 + 0) * 32];
        float4 w1 = Wc[(k0 + 1) * 32];
        float4 w2 = Wc[(k0 + 2) * 32];
        float4 w3 = Wc[(k0 + 3) * 32];
        #pragma unroll
        for (int r = 0; r < 8; ++r) {
            float4 xr = *(const float4*)&xs[(8 * ty + r) * FF + k0];
            float4 a = acc[r];
            a.x = fmaf(xr.x, w0.x, a.x); a.y = fmaf(xr.x, w0.y, a.y);
            a.z = fmaf(xr.x, w0.z, a.z); a.w = fmaf(xr.x, w0.w, a.w);
            a.x = fmaf(xr.y, w1.x, a.x); a.y = fmaf(xr.y, w1.y, a.y);
            a.z = fmaf(xr.y, w1.z, a.z); a.w = fmaf(xr.y, w1.w, a.w);
            a.x = fmaf(xr.z, w2.x, a.x); a.y = fmaf(xr.z, w2.y, a.y);
            a.z = fmaf(xr.z, w2.z, a.z); a.w = fmaf(xr.z, w2.w, a.w);
            a.x = fmaf(xr.w, w3.x, a.x); a.y = fmaf(xr.w, w3.y, a.y);
            a.z = fmaf(xr.w, w3.z, a.z); a.w = fmaf(xr.w, w3.w, a.w);
            acc[r] = a;
        }
    }

    #pragma unroll
    for (int r = 0; r < 8; ++r) {
        int row = row0 + 8 * ty + r;
        if (row < n_rows) {
            float4 o = make_float4(acc[r].x + bv.x, acc[r].y + bv.y,
                                   acc[r].z + bv.z, acc[r].w + bv.w);
            *(float4*)&Y[(size_t)row * UU + 4 * tx] = o;
        }
    }
}

__device__ __forceinline__ void stage_x_tile(
    const float* __restrict__ X, float* xs, int row0, int n_rows, int t)
{
    const float4* xt = (const float4*)(X + (size_t)row0 * FF);
    float4* xs4 = (float4*)xs;
    const int lim = (n_rows - row0) * (FF / 4);
    #pragma unroll
    for (int j = 0; j < 8; ++j) {
        int idx = t + j * 256;
        float4 v = make_float4(0.f, 0.f, 0.f, 0.f);
        if (idx < lim) v = xt[idx];
        xs4[idx] = v;
    }
    __syncthreads();
}

// Fused: stage X tile once, compute self-GEMM (into out, +bias) and the 8
// relation GEMMs (into hr planes) from the same LDS tile.
__global__ __launch_bounds__(256, 2) void gemm_nine_kernel(
    const float* __restrict__ X, const float* __restrict__ Wself,
    const float* __restrict__ Wrel, const float* __restrict__ bias,
    float* __restrict__ out, float* __restrict__ hr)
{
    __shared__ float xs[64 * FF];
    const int t = threadIdx.x;
    const int row0 = blockIdx.x * 64;
    stage_x_tile(X, xs, row0, NN, t);

    const int tx = t & 31;
    const int ty = t >> 5;
    const float4 bv = *(const float4*)&bias[4 * tx];
    const float4 zv = make_float4(0.f, 0.f, 0.f, 0.f);

    #pragma unroll 1
    for (int m = 0; m < 1 + NREL; ++m) {
        const float* W = (m == 0) ? Wself : Wrel + (size_t)(m - 1) * FF * UU;
        float* Y = (m == 0) ? out : hr + (size_t)(m - 1) * (size_t)NN * UU;
        gemm_tile_compute(xs, W, (m == 0) ? bv : zv, Y, row0, NN, tx, ty);
    }
}

// Fallback single-matrix GEMM (used when d_ws is too small for 8 planes)
__global__ __launch_bounds__(256, 2) void gemm_one_kernel(
    const float* __restrict__ X, const float* __restrict__ W,
    const float* __restrict__ bias, float* __restrict__ Y, int n_rows)
{
    __shared__ float xs[64 * FF];
    const int t = threadIdx.x;
    const int row0 = blockIdx.x * 64;
    stage_x_tile(X, xs, row0, n_rows, t);

    const int tx = t & 31;
    const int ty = t >> 5;
    float4 bv = make_float4(0.f, 0.f, 0.f, 0.f);
    if (bias) bv = *(const float4*)&bias[4 * tx];
    gemm_tile_compute(xs, W, bv, Y, row0, n_rows, tx, ty);
}

// One wave per edge (grid-strided). rel = e / NE picks the hr plane.
// hr is the base of the plane array; for the fallback path pass the single
// plane and ntot = NE (rel evaluates to 0).
__global__ __launch_bounds__(256, 8) void scatter_kernel(
    const float* __restrict__ hr, const int* __restrict__ src,
    const int* __restrict__ dst, const float* __restrict__ w,
    float* __restrict__ out, int ntot)
{
    const int wid = (blockIdx.x * 256 + threadIdx.x) >> 6;
    const int nw = (gridDim.x * 256) >> 6;
    const int lane = threadIdx.x & 63;
    for (int e = wid; e < ntot; e += nw) {
        int rel = e / NE;                      // const divisor -> magic mul
        int s = src[e];
        int d = dst[e];
        float we = w[e];
        const float2 v = ((const float2*)(hr + ((size_t)rel * NN + s) * UU))[lane];
        float* orow = out + (size_t)d * UU;
        atomicAdd(&orow[2 * lane + 0], v.x * we);
        atomicAdd(&orow[2 * lane + 1], v.y * we);
    }
}

__global__ __launch_bounds__(256, 8) void relu_kernel(float* __restrict__ y, int n4)
{
    int i = blockIdx.x * 256 + threadIdx.x;
    if (i < n4) {
        float4 v = ((float4*)y)[i];
        v.x = fmaxf(v.x, 0.f);
        v.y = fmaxf(v.y, 0.f);
        v.z = fmaxf(v.z, 0.f);
        v.w = fmaxf(v.w, 0.f);
        ((float4*)y)[i] = v;
    }
}

extern "C" void kernel_launch(void* const* d_in, const int* in_sizes, int n_in,
                              void* d_out, int out_size, void* d_ws, size_t ws_size,
                              hipStream_t stream) {
    const float* X     = (const float*)d_in[0];  // [1,50000,128]
    const int*   esrc  = (const int*)d_in[1];    // [8,60000]
    const int*   edst  = (const int*)d_in[2];    // [8,60000]
    const float* ew    = (const float*)d_in[3];  // [8,60000]
    const float* Wself = (const float*)d_in[4];  // [128,128]
    const float* Wrel  = (const float*)d_in[5];  // [8,128,128]
    const float* bias  = (const float*)d_in[6];  // [128]
    float* out = (float*)d_out;                  // [1,50000,128] fp32 accumulator
    float* hr  = (float*)d_ws;

    const size_t plane = (size_t)NN * UU;        // elements per hr plane
    const int gemm_grid = (NN + 63) / 64;        // 782
    const bool fused = ws_size >= plane * NREL * sizeof(float);  // 204.8 MB

    if (fused) {
        hipLaunchKernelGGL(gemm_nine_kernel, dim3(gemm_grid), dim3(256), 0, stream,
                           X, Wself, Wrel, bias, out, hr);
        hipLaunchKernelGGL(scatter_kernel, dim3(4096), dim3(256), 0, stream,
                           hr, esrc, edst, ew, out, NREL * NE);
    } else {
        hipLaunchKernelGGL(gemm_one_kernel, dim3(gemm_grid), dim3(256), 0, stream,
                           X, Wself, bias, out, NN);
        for (int r = 0; r < NREL; ++r) {
            hipLaunchKernelGGL(gemm_one_kernel, dim3(gemm_grid), dim3(256), 0, stream,
                               X, Wrel + (size_t)r * FF * UU, (const float*)nullptr, hr, NN);
            hipLaunchKernelGGL(scatter_kernel, dim3(2048), dim3(256), 0, stream,
                               hr, esrc + r * NE, edst + r * NE, ew + r * NE, out, NE);
        }
    }

    hipLaunchKernelGGL(relu_kernel, dim3((NN * UU / 4 + 255) / 256), dim3(256), 0, stream,
                       out, NN * UU / 4);
}

// Round 4
// 625.225 us; speedup vs baseline: 14.0247x; 1.0089x over previous
//
#include <hip/hip_runtime.h>

#define NN 50000
#define FF 128
#define UU 128
#define NREL 8
#define NE 60000
#define NKEY (NREL * NN)        // 400000 (rel,dst) keys
#define NEDGE_TOT (NREL * NE)   // 480000
#define NB ((NKEY + 255) / 256) // 1563 scan blocks

// ---------------- CSR build ----------------

__global__ __launch_bounds__(256) void zero_kernel(int* __restrict__ p, int n)
{
    int i = blockIdx.x * 256 + threadIdx.x;
    if (i < n) p[i] = 0;
}

__global__ __launch_bounds__(256) void count_kernel(
    const int* __restrict__ edst, int* __restrict__ cnt)
{
    int i = blockIdx.x * 256 + threadIdx.x;
    if (i < NEDGE_TOT) {
        int rel = i / NE;
        atomicAdd(&cnt[rel * NN + edst[i]], 1);
    }
}

// per-256-block exclusive scan; write block totals
__global__ __launch_bounds__(256) void scanA_kernel(
    const int* __restrict__ cnt, int* __restrict__ off, int* __restrict__ bsums)
{
    __shared__ int s0[256], s1[256];
    const int t = threadIdx.x;
    const int gi = blockIdx.x * 256 + t;
    s0[t] = (gi < NKEY) ? cnt[gi] : 0;
    __syncthreads();
    int* src = s0; int* dst = s1;
    #pragma unroll
    for (int d = 1; d < 256; d <<= 1) {
        dst[t] = src[t] + (t >= d ? src[t - d] : 0);
        __syncthreads();
        int* tmp = src; src = dst; dst = tmp;
    }
    if (gi < NKEY) off[gi] = (t ? src[t - 1] : 0);
    if (t == 255) bsums[blockIdx.x] = src[255];
}

// single-block exclusive scan of the 1563 block sums (padded to 2048)
__global__ __launch_bounds__(256) void scanB_kernel(int* __restrict__ bsums)
{
    __shared__ int s0[2048], s1[2048];
    const int t = threadIdx.x;
    for (int i = t; i < 2048; i += 256) s0[i] = (i < NB) ? bsums[i] : 0;
    __syncthreads();
    int* src = s0; int* dst = s1;
    for (int d = 1; d < 2048; d <<= 1) {
        for (int i = t; i < 2048; i += 256)
            dst[i] = src[i] + (i >= d ? src[i - d] : 0);
        __syncthreads();
        int* tmp = src; src = dst; dst = tmp;
    }
    for (int i = t; i < 2048; i += 256)
        if (i < NB) bsums[i] = (i ? src[i - 1] : 0);
}

// add scanned block sums; init cursor copy; set sentinel off[NKEY]
__global__ __launch_bounds__(256) void scanC_kernel(
    int* __restrict__ off, const int* __restrict__ bsums, int* __restrict__ cur)
{
    int gi = blockIdx.x * 256 + threadIdx.x;
    if (gi < NKEY) {
        int v = off[gi] + bsums[gi >> 8];
        off[gi] = v;
        cur[gi] = v;
    }
    if (gi == 0) off[NKEY] = NEDGE_TOT;
}

__global__ __launch_bounds__(256) void fill_kernel(
    const int* __restrict__ edst, int* __restrict__ cur, int* __restrict__ eids)
{
    int i = blockIdx.x * 256 + threadIdx.x;
    if (i < NEDGE_TOT) {
        int rel = i / NE;
        int pos = atomicAdd(&cur[rel * NN + edst[i]], 1);
        eids[pos] = i;
    }
}

// ---------------- fused RGCN kernel ----------------

// accumulate acc += xs(64x128) @ W(128x128); lane tx owns cols 4tx..4tx+3,
// ty owns rows 8ty..8ty+7. All static indices -> registers.
__device__ __forceinline__ void gemm_tile_accum(
    const float* xs, const float* __restrict__ W, float4 (&acc)[8], int tx, int ty)
{
    const float4* Wc = (const float4*)W + tx;
    #pragma unroll 2
    for (int k0 = 0; k0 < FF; k0 += 4) {
        float4 w0 = Wc[(k0 + 0) * 32];
        float4 w1 = Wc[(k0 + 1) * 32];
        float4 w2 = Wc[(k0 + 2) * 32];
        float4 w3 = Wc[(k0 + 3) * 32];
        #pragma unroll
        for (int r = 0; r < 8; ++r) {
            float4 xr = *(const float4*)&xs[(8 * ty + r) * FF + k0];
            float4 a = acc[r];
            a.x = fmaf(xr.x, w0.x, a.x); a.y = fmaf(xr.x, w0.y, a.y);
            a.z = fmaf(xr.x, w0.z, a.z); a.w = fmaf(xr.x, w0.w, a.w);
            a.x = fmaf(xr.y, w1.x, a.x); a.y = fmaf(xr.y, w1.y, a.y);
            a.z = fmaf(xr.y, w1.z, a.z); a.w = fmaf(xr.y, w1.w, a.w);
            a.x = fmaf(xr.z, w2.x, a.x); a.y = fmaf(xr.z, w2.y, a.y);
            a.z = fmaf(xr.z, w2.z, a.z); a.w = fmaf(xr.z, w2.w, a.w);
            a.x = fmaf(xr.w, w3.x, a.x); a.y = fmaf(xr.w, w3.y, a.y);
            a.z = fmaf(xr.w, w3.z, a.z); a.w = fmaf(xr.w, w3.w, a.w);
            acc[r] = a;
        }
    }
}

__global__ __launch_bounds__(256, 2) void rgcn_fused_kernel(
    const float* __restrict__ X, const int* __restrict__ esrc,
    const int* __restrict__ edst, const float* __restrict__ ew,
    const float* __restrict__ Wself, const float* __restrict__ Wrel,
    const float* __restrict__ bias, const int* __restrict__ off,
    const int* __restrict__ eids, float* __restrict__ out)
{
    __shared__ float xs[64 * FF];   // X tile (self term)
    __shared__ float zs[64 * FF];   // aggregated-feature tile (per relation)

    const int t = threadIdx.x;
    const int row0 = blockIdx.x * 64;
    const int wid = t >> 6;
    const int lane = t & 63;
    const int tx = t & 31;
    const int ty = t >> 5;

    // stage X tile (coalesced float4)
    {
        const float4* xt = (const float4*)(X + (size_t)row0 * FF);
        float4* xs4 = (float4*)xs;
        const int lim = (NN - row0) * (FF / 4);
        #pragma unroll
        for (int j = 0; j < 8; ++j) {
            int idx = t + j * 256;
            float4 v = make_float4(0.f, 0.f, 0.f, 0.f);
            if (idx < lim) v = xt[idx];
            xs4[idx] = v;
        }
    }
    __syncthreads();

    float4 acc[8];
    #pragma unroll
    for (int r = 0; r < 8; ++r) acc[r] = make_float4(0.f, 0.f, 0.f, 0.f);

    // self-loop term
    gemm_tile_accum(xs, Wself, acc, tx, ty);

    const int rowEndIdx = (row0 + 64 < NN) ? (row0 + 64) : NN;

    for (int rel = 0; rel < NREL; ++rel) {
        __syncthreads();                 // previous GEMM done reading zs
        // zero Z tile
        float4* zs4 = (float4*)zs;
        #pragma unroll
        for (int i = 0; i < 8; ++i) zs4[t + i * 256] = make_float4(0.f, 0.f, 0.f, 0.f);
        __syncthreads();

        // gather-accumulate w * X[src] into Z rows (LDS atomics; waves stride edges)
        const int seg0 = off[rel * NN + row0];
        const int seg1 = off[rel * NN + rowEndIdx];
        for (int j = seg0 + wid; j < seg1; j += 4) {
            int eid = eids[j];
            int s = esrc[eid];
            int d = edst[eid];
            float we = ew[eid];
            float2 v = ((const float2*)(X + (size_t)s * FF))[lane];
            int zb = (d - row0) * FF + 2 * lane;
            atomicAdd(&zs[zb + 0], v.x * we);
            atomicAdd(&zs[zb + 1], v.y * we);
        }
        __syncthreads();

        // acc += Z @ W_rel
        gemm_tile_accum(zs, Wrel + (size_t)rel * FF * UU, acc, tx, ty);
    }

    // epilogue: bias + relu + store
    const float4 bv = *(const float4*)&bias[4 * tx];
    #pragma unroll
    for (int r = 0; r < 8; ++r) {
        int row = row0 + 8 * ty + r;
        if (row < NN) {
            float4 o;
            o.x = fmaxf(acc[r].x + bv.x, 0.f);
            o.y = fmaxf(acc[r].y + bv.y, 0.f);
            o.z = fmaxf(acc[r].z + bv.z, 0.f);
            o.w = fmaxf(acc[r].w + bv.w, 0.f);
            *(float4*)&out[(size_t)row * UU + 4 * tx] = o;
        }
    }
}

// ---------------- launch ----------------

extern "C" void kernel_launch(void* const* d_in, const int* in_sizes, int n_in,
                              void* d_out, int out_size, void* d_ws, size_t ws_size,
                              hipStream_t stream) {
    const float* X     = (const float*)d_in[0];  // [1,50000,128]
    const int*   esrc  = (const int*)d_in[1];    // [8,60000] flat
    const int*   edst  = (const int*)d_in[2];    // [8,60000] flat
    const float* ew    = (const float*)d_in[3];  // [8,60000] flat
    const float* Wself = (const float*)d_in[4];  // [128,128]
    const float* Wrel  = (const float*)d_in[5];  // [8,128,128]
    const float* bias  = (const float*)d_in[6];  // [128]
    float* out = (float*)d_out;                  // [1,50000,128]

    // ws layout (ints): off[NKEY+1] | cur[NKEY] | eids[NEDGE_TOT] | bsums[NB]
    int* off   = (int*)d_ws;
    int* cur   = off + (NKEY + 1);
    int* eids  = cur + NKEY;
    int* bsums = eids + NEDGE_TOT;

    const int gKey  = (NKEY + 255) / 256;       // 1563
    const int gEdge = (NEDGE_TOT + 255) / 256;  // 1875
    const int gTile = (NN + 63) / 64;           // 782

    hipLaunchKernelGGL(zero_kernel,  dim3(gKey),  dim3(256), 0, stream, cur, NKEY);
    hipLaunchKernelGGL(count_kernel, dim3(gEdge), dim3(256), 0, stream, edst, cur);
    hipLaunchKernelGGL(scanA_kernel, dim3(gKey),  dim3(256), 0, stream, cur, off, bsums);
    hipLaunchKernelGGL(scanB_kernel, dim3(1),     dim3(256), 0, stream, bsums);
    hipLaunchKernelGGL(scanC_kernel, dim3(gKey),  dim3(256), 0, stream, off, bsums, cur);
    hipLaunchKernelGGL(fill_kernel,  dim3(gEdge), dim3(256), 0, stream, edst, cur, eids);

    hipLaunchKernelGGL(rgcn_fused_kernel, dim3(gTile), dim3(256), 0, stream,
                       X, esrc, edst, ew, Wself, Wrel, bias, off, eids, out);
}

// Round 5
// 560.679 us; speedup vs baseline: 15.6392x; 1.1151x over previous
//
#include <hip/hip_runtime.h>
#include <hip/hip_bf16.h>

#define NN 50000
#define FF 128
#define UU 128
#define NREL 8
#define NE 60000
#define NKEY (NREL * NN)        // 400000
#define NET (NREL * NE)         // 480000
#define NB ((NKEY + 255) / 256) // 1563

typedef __attribute__((ext_vector_type(8))) short bf16x8;
typedef __attribute__((ext_vector_type(4))) float f32x4;

// ---------------- CSR build ----------------

__global__ __launch_bounds__(256) void zero_kernel(int* __restrict__ p, int n)
{
    int i = blockIdx.x * 256 + threadIdx.x;
    if (i < n) p[i] = 0;
}

__global__ __launch_bounds__(256) void count_kernel(
    const int* __restrict__ edst, int* __restrict__ cnt)
{
    int i = blockIdx.x * 256 + threadIdx.x;
    if (i < NET) {
        int rel = i / NE;
        atomicAdd(&cnt[rel * NN + edst[i]], 1);
    }
}

__global__ __launch_bounds__(256) void scanA_kernel(
    const int* __restrict__ cnt, int* __restrict__ off, int* __restrict__ bsums)
{
    __shared__ int s0[256], s1[256];
    const int t = threadIdx.x;
    const int gi = blockIdx.x * 256 + t;
    s0[t] = (gi < NKEY) ? cnt[gi] : 0;
    __syncthreads();
    int* src = s0; int* dst = s1;
    #pragma unroll
    for (int d = 1; d < 256; d <<= 1) {
        dst[t] = src[t] + (t >= d ? src[t - d] : 0);
        __syncthreads();
        int* tmp = src; src = dst; dst = tmp;
    }
    if (gi < NKEY) off[gi] = (t ? src[t - 1] : 0);
    if (t == 255) bsums[blockIdx.x] = src[255];
}

__global__ __launch_bounds__(256) void scanB_kernel(int* __restrict__ bsums)
{
    __shared__ int s0[2048], s1[2048];
    const int t = threadIdx.x;
    for (int i = t; i < 2048; i += 256) s0[i] = (i < NB) ? bsums[i] : 0;
    __syncthreads();
    int* src = s0; int* dst = s1;
    for (int d = 1; d < 2048; d <<= 1) {
        for (int i = t; i < 2048; i += 256)
            dst[i] = src[i] + (i >= d ? src[i - d] : 0);
        __syncthreads();
        int* tmp = src; src = dst; dst = tmp;
    }
    for (int i = t; i < 2048; i += 256)
        if (i < NB) bsums[i] = (i ? src[i - 1] : 0);
}

__global__ __launch_bounds__(256) void scanC_kernel(
    int* __restrict__ off, const int* __restrict__ bsums, int* __restrict__ cur)
{
    int gi = blockIdx.x * 256 + threadIdx.x;
    if (gi < NKEY) {
        int v = off[gi] + bsums[gi >> 8];
        off[gi] = v;
        cur[gi] = v;
    }
    if (gi == 0) off[NKEY] = NET;
}

// CSR-ordered edge records (SoA) so the gather phase reads contiguously.
__global__ __launch_bounds__(256) void fill_kernel(
    const int* __restrict__ esrc, const int* __restrict__ edst,
    const float* __restrict__ ew, int* __restrict__ cur,
    int* __restrict__ gsrc, int* __restrict__ gdst, float* __restrict__ gw)
{
    int i = blockIdx.x * 256 + threadIdx.x;
    if (i < NET) {
        int rel = i / NE;
        int d = edst[i];
        int pos = atomicAdd(&cur[rel * NN + d], 1);
        gsrc[pos] = esrc[i];
        gdst[pos] = d;
        gw[pos] = ew[i];
    }
}

// ---------------- dtype converts ----------------

__global__ __launch_bounds__(256) void xb_kernel(const float* __restrict__ X,
                                                 ushort* __restrict__ Xb)
{
    int i = blockIdx.x * 256 + threadIdx.x;   // one float4 -> 4 bf16
    if (i < NN * FF / 4) {
        float4 v = ((const float4*)X)[i];
        union { __hip_bfloat162 h[2]; uint2 u; } p;
        p.h[0] = __float22bfloat162_rn(make_float2(v.x, v.y));
        p.h[1] = __float22bfloat162_rn(make_float2(v.z, v.w));
        ((uint2*)Xb)[i] = p.u;
    }
}

// Wt[m][col][k] = bf16(W_m[k][col]); m=0 self, m=1..8 relations
__global__ __launch_bounds__(256) void wt_kernel(const float* __restrict__ Wself,
    const float* __restrict__ Wrel, ushort* __restrict__ Wt)
{
    int i = blockIdx.x * 256 + threadIdx.x;
    if (i < 9 * FF * UU) {
        int m = i >> 14, rem = i & 16383;
        int col = rem >> 7, k = rem & 127;
        float v = (m == 0) ? Wself[k * UU + col]
                           : Wrel[(size_t)(m - 1) * FF * UU + k * UU + col];
        __hip_bfloat16 h = __float2bfloat16(v);
        Wt[i] = *(ushort*)&h;
    }
}

// ---------------- fused RGCN (MFMA) ----------------
// Block: 256 thr (4 waves), tile 64 rows x 128 cols. zs = fp32 Z tile, 16B-slot
// XOR swizzled (slot ^= row&7) so A-frag ds_read_b128 are bank-uniform.
// Wave w: rows 16w..16w+15 (8 col-tiles of 16x16, K=128 = 4 ksteps of 32).

__global__ __launch_bounds__(256, 4) void rgcn_fused_kernel(
    const float* __restrict__ X, const ushort* __restrict__ Xb,
    const ushort* __restrict__ Wt, const float* __restrict__ bias,
    const int* __restrict__ off, const int* __restrict__ gsrc,
    const int* __restrict__ gdst, const float* __restrict__ gw,
    float* __restrict__ out)
{
    __shared__ float zs[64 * FF];   // 32 KB
    const int t = threadIdx.x;
    const int row0 = blockIdx.x * 64;
    const int rowEnd = (row0 + 64 < NN) ? row0 + 64 : NN;
    const int lane = t & 63;
    const int wid = t >> 6;

    const int al = lane & 15;       // A row / B col / D col within 16
    const int ag = lane >> 4;       // k-group (8 k's each)
    const int arow = 16 * wid + al; // A-frag row within tile

    f32x4 acc[8];
    #pragma unroll
    for (int c = 0; c < 8; ++c) acc[c] = (f32x4){0.f, 0.f, 0.f, 0.f};

    for (int m = 0; m < 1 + NREL; ++m) {
        __syncthreads();            // previous MFMA done reading zs
        if (m == 0) {
            // stage fp32 X tile (self term), swizzled
            const float4* xt = (const float4*)(X + (size_t)row0 * FF);
            const int lim = (rowEnd - row0) * 32;
            #pragma unroll
            for (int i2 = 0; i2 < 8; ++i2) {
                int idx = t + i2 * 256;
                float4 v = make_float4(0.f, 0.f, 0.f, 0.f);
                if (idx < lim) v = xt[idx];
                int r = idx >> 5, sl = idx & 31;
                ((float4*)zs)[r * 32 + (sl ^ (r & 7))] = v;
            }
        } else {
            #pragma unroll
            for (int i2 = 0; i2 < 8; ++i2)
                ((float4*)zs)[t + i2 * 256] = make_float4(0.f, 0.f, 0.f, 0.f);
            __syncthreads();
            const int rel = m - 1;
            const int seg0 = off[rel * NN + row0];
            const int seg1 = off[rel * NN + rowEnd];
            const int kb = (lane >> 1);           // 16B slot of this lane's 2 floats
            const int kw = (lane & 1) << 1;       // offset within slot
            int j = seg0 + wid;
            for (; j + 4 < seg1; j += 8) {        // 2 independent edges in flight
                int s0 = gsrc[j],     s1 = gsrc[j + 4];
                int r0 = gdst[j] - row0, r1 = gdst[j + 4] - row0;
                float w0 = gw[j],     w1 = gw[j + 4];
                uint x0 = *(const uint*)(Xb + (size_t)s0 * FF + 2 * lane);
                uint x1 = *(const uint*)(Xb + (size_t)s1 * FF + 2 * lane);
                int f0 = r0 * FF + (((kb ^ (r0 & 7)) << 2) | kw);
                int f1 = r1 * FF + (((kb ^ (r1 & 7)) << 2) | kw);
                atomicAdd(&zs[f0],     __uint_as_float(x0 << 16) * w0);
                atomicAdd(&zs[f0 + 1], __uint_as_float(x0 & 0xffff0000u) * w0);
                atomicAdd(&zs[f1],     __uint_as_float(x1 << 16) * w1);
                atomicAdd(&zs[f1 + 1], __uint_as_float(x1 & 0xffff0000u) * w1);
            }
            if (j < seg1) {
                int s0 = gsrc[j];
                int r0 = gdst[j] - row0;
                float w0 = gw[j];
                uint x0 = *(const uint*)(Xb + (size_t)s0 * FF + 2 * lane);
                int f0 = r0 * FF + (((kb ^ (r0 & 7)) << 2) | kw);
                atomicAdd(&zs[f0],     __uint_as_float(x0 << 16) * w0);
                atomicAdd(&zs[f0 + 1], __uint_as_float(x0 & 0xffff0000u) * w0);
            }
        }
        __syncthreads();

        // A fragments: lane row=arow, k = s*32 + ag*8 + {0..7} (contiguous)
        bf16x8 afr[4];
        #pragma unroll
        for (int s = 0; s < 4; ++s) {
            int sl0 = s * 8 + ag * 2;
            float4 f0 = *(const float4*)&zs[arow * FF + ((sl0 ^ (arow & 7)) << 2)];
            float4 f1 = *(const float4*)&zs[arow * FF + (((sl0 + 1) ^ (arow & 7)) << 2)];
            union { __hip_bfloat162 h[4]; bf16x8 v; } u;
            u.h[0] = __float22bfloat162_rn(make_float2(f0.x, f0.y));
            u.h[1] = __float22bfloat162_rn(make_float2(f0.z, f0.w));
            u.h[2] = __float22bfloat162_rn(make_float2(f1.x, f1.y));
            u.h[3] = __float22bfloat162_rn(make_float2(f1.z, f1.w));
            afr[s] = u.v;
        }
        // B frags from Wt[m][col][k] (contiguous short8), 8 col-tiles x 4 ksteps
        const ushort* Wm = Wt + (size_t)m * FF * UU;
        #pragma unroll
        for (int c = 0; c < 8; ++c) {
            const bf16x8* bp = (const bf16x8*)(Wm + (c * 16 + al) * FF);
            #pragma unroll
            for (int s = 0; s < 4; ++s) {
                acc[c] = __builtin_amdgcn_mfma_f32_16x16x32_bf16(
                    afr[s], bp[s * 4 + ag], acc[c], 0, 0, 0);
            }
        }
    }

    // epilogue: D layout col=lane&15, row=(lane>>4)*4+reg
    const int drow = 16 * wid + ag * 4;
    #pragma unroll
    for (int c = 0; c < 8; ++c) {
        int col = c * 16 + al;
        float b = bias[col];
        #pragma unroll
        for (int q = 0; q < 4; ++q) {
            int row = row0 + drow + q;
            if (row < NN)
                out[(size_t)row * UU + col] = fmaxf(acc[c][q] + b, 0.f);
        }
    }
}

// ---------------- launch ----------------

extern "C" void kernel_launch(void* const* d_in, const int* in_sizes, int n_in,
                              void* d_out, int out_size, void* d_ws, size_t ws_size,
                              hipStream_t stream) {
    const float* X     = (const float*)d_in[0];
    const int*   esrc  = (const int*)d_in[1];
    const int*   edst  = (const int*)d_in[2];
    const float* ew    = (const float*)d_in[3];
    const float* Wself = (const float*)d_in[4];
    const float* Wrel  = (const float*)d_in[5];
    const float* bias  = (const float*)d_in[6];
    float* out = (float*)d_out;

    // ws layout (16B-aligned segments)
    int*    off   = (int*)d_ws;            // NKEY+1 (padded to 400004)
    int*    cur   = off + 400004;          // NKEY
    int*    bsums = cur + NKEY;            // NB (padded to 1568)
    int*    gsrc  = bsums + 1568;          // NET
    int*    gdst  = gsrc + NET;            // NET
    float*  gw    = (float*)(gdst + NET);  // NET
    ushort* Xb    = (ushort*)(gw + NET);   // NN*FF bf16
    ushort* Wt    = Xb + (size_t)NN * FF;  // 9*FF*UU bf16

    const int gKey  = (NKEY + 255) / 256;  // 1563
    const int gEdge = (NET + 255) / 256;   // 1875
    const int gTile = (NN + 63) / 64;      // 782

    hipLaunchKernelGGL(zero_kernel,  dim3(gKey),  dim3(256), 0, stream, cur, NKEY);
    hipLaunchKernelGGL(count_kernel, dim3(gEdge), dim3(256), 0, stream, edst, cur);
    hipLaunchKernelGGL(scanA_kernel, dim3(gKey),  dim3(256), 0, stream, cur, off, bsums);
    hipLaunchKernelGGL(scanB_kernel, dim3(1),     dim3(256), 0, stream, bsums);
    hipLaunchKernelGGL(scanC_kernel, dim3(gKey),  dim3(256), 0, stream, off, bsums, cur);
    hipLaunchKernelGGL(fill_kernel,  dim3(gEdge), dim3(256), 0, stream,
                       esrc, edst, ew, cur, gsrc, gdst, gw);
    hipLaunchKernelGGL(xb_kernel,    dim3((NN * FF / 4 + 255) / 256), dim3(256), 0, stream, X, Xb);
    hipLaunchKernelGGL(wt_kernel,    dim3((9 * FF * UU + 255) / 256), dim3(256), 0, stream,
                       Wself, Wrel, Wt);

    hipLaunchKernelGGL(rgcn_fused_kernel, dim3(gTile), dim3(256), 0, stream,
                       X, Xb, Wt, bias, off, gsrc, gdst, gw, out);
}

// Round 6
// 304.779 us; speedup vs baseline: 28.7703x; 1.8396x over previous
//
#include <hip/hip_runtime.h>
#include <hip/hip_bf16.h>

#define NN 50000
#define FF 128
#define UU 128
#define NREL 8
#define NE 60000
#define NKEY (NREL * NN)        // 400000
#define NET (NREL * NE)         // 480000
#define NB ((NKEY + 255) / 256) // 1563

typedef __attribute__((ext_vector_type(8))) short bf16x8;
typedef __attribute__((ext_vector_type(4))) float f32x4;

// ---------------- prep: zero cursors + X->bf16 + W->bf16 transposed ----------------

__global__ __launch_bounds__(256) void prep_kernel(
    const float* __restrict__ X, const float* __restrict__ Wself,
    const float* __restrict__ Wrel, ushort* __restrict__ Xb,
    ushort* __restrict__ Wt, int* __restrict__ cur)
{
    int i = blockIdx.x * 256 + threadIdx.x;
    if (i < NN * FF / 4) {
        float4 v = ((const float4*)X)[i];
        union { __hip_bfloat162 h[2]; uint2 u; } p;
        p.h[0] = __float22bfloat162_rn(make_float2(v.x, v.y));
        p.h[1] = __float22bfloat162_rn(make_float2(v.z, v.w));
        ((uint2*)Xb)[i] = p.u;
    }
    if (i < NKEY) cur[i] = 0;
    if (i < 9 * FF * UU) {
        int m = i >> 14, rem = i & 16383;
        int col = rem >> 7, k = rem & 127;
        float v = (m == 0) ? Wself[k * UU + col]
                           : Wrel[(size_t)(m - 1) * FF * UU + k * UU + col];
        __hip_bfloat16 h = __float2bfloat16(v);
        Wt[i] = *(ushort*)&h;
    }
}

// ---------------- CSR build ----------------

__global__ __launch_bounds__(256) void count_kernel(
    const int* __restrict__ edst, int* __restrict__ cnt)
{
    int i = blockIdx.x * 256 + threadIdx.x;
    if (i < NET) {
        int rel = i / NE;
        atomicAdd(&cnt[rel * NN + edst[i]], 1);
    }
}

__global__ __launch_bounds__(256) void scanA_kernel(
    const int* __restrict__ cnt, int* __restrict__ off, int* __restrict__ bsums)
{
    __shared__ int s0[256], s1[256];
    const int t = threadIdx.x;
    const int gi = blockIdx.x * 256 + t;
    s0[t] = (gi < NKEY) ? cnt[gi] : 0;
    __syncthreads();
    int* src = s0; int* dst = s1;
    #pragma unroll
    for (int d = 1; d < 256; d <<= 1) {
        dst[t] = src[t] + (t >= d ? src[t - d] : 0);
        __syncthreads();
        int* tmp = src; src = dst; dst = tmp;
    }
    if (gi < NKEY) off[gi] = (t ? src[t - 1] : 0);
    if (t == 255) bsums[blockIdx.x] = src[255];
}

__global__ __launch_bounds__(256) void scanB_kernel(int* __restrict__ bsums)
{
    __shared__ int s0[2048], s1[2048];
    const int t = threadIdx.x;
    for (int i = t; i < 2048; i += 256) s0[i] = (i < NB) ? bsums[i] : 0;
    __syncthreads();
    int* src = s0; int* dst = s1;
    for (int d = 1; d < 2048; d <<= 1) {
        for (int i = t; i < 2048; i += 256)
            dst[i] = src[i] + (i >= d ? src[i - d] : 0);
        __syncthreads();
        int* tmp = src; src = dst; dst = tmp;
    }
    for (int i = t; i < 2048; i += 256)
        if (i < NB) bsums[i] = (i ? src[i - 1] : 0);
}

__global__ __launch_bounds__(256) void scanC_kernel(
    int* __restrict__ off, const int* __restrict__ bsums, int* __restrict__ cur)
{
    int gi = blockIdx.x * 256 + threadIdx.x;
    if (gi < NKEY) {
        int v = off[gi] + bsums[gi >> 8];
        off[gi] = v;
        cur[gi] = v;
    }
    if (gi == 0) off[NKEY] = NET;
}

__global__ __launch_bounds__(256) void fill_kernel(
    const int* __restrict__ esrc, const int* __restrict__ edst,
    const float* __restrict__ ew, int* __restrict__ cur,
    int* __restrict__ gsrc, float* __restrict__ gw)
{
    int i = blockIdx.x * 256 + threadIdx.x;
    if (i < NET) {
        int rel = i / NE;
        int pos = atomicAdd(&cur[rel * NN + edst[i]], 1);
        gsrc[pos] = esrc[i];
        gw[pos] = ew[i];
    }
}

// ---------------- pass 1: per-(rel,dst) aggregation, one wave per key ----------------
// Zb[key][0:128) = bf16( sum_{edges of key} w * X[src] ); zeros if no edges.

__global__ __launch_bounds__(256) void agg_kernel(
    const ushort* __restrict__ Xb, const int* __restrict__ off,
    const int* __restrict__ gsrc, const float* __restrict__ gw,
    ushort* __restrict__ Zb)
{
    const int key = blockIdx.x * 4 + (threadIdx.x >> 6);
    const int lane = threadIdx.x & 63;
    const int j0 = off[key];
    const int j1 = off[key + 1];
    float ax = 0.f, ay = 0.f;
    for (int j = j0; j < j1; ++j) {
        int s = gsrc[j];
        float w = gw[j];
        uint x = *(const uint*)(Xb + (size_t)s * FF + 2 * lane);
        ax = fmaf(__uint_as_float(x << 16), w, ax);
        ay = fmaf(__uint_as_float(x & 0xffff0000u), w, ay);
    }
    __hip_bfloat162 h = __float22bfloat162_rn(make_float2(ax, ay));
    *(uint*)(Zb + (size_t)key * FF + 2 * lane) = *(uint*)&h;
}

// ---------------- pass 2: GEMM, one independent wave per 16 output rows ----------------
// No LDS, no barriers. A-frag: lane al=lane&15 -> row R0+al, ag=lane>>4 -> k
// group; contiguous short8 at [row*128 + s*32 + ag*8]. B from Wt[m][col][k].
// D: col = c*16+al, row = R0 + ag*4 + q  (verified layout from round 5).

__global__ __launch_bounds__(256, 4) void gemm_kernel(
    const ushort* __restrict__ Xb, const ushort* __restrict__ Zb,
    const ushort* __restrict__ Wt, const float* __restrict__ bias,
    float* __restrict__ out)
{
    const int gwid = blockIdx.x * 4 + (threadIdx.x >> 6);
    if (gwid >= NN / 16) return;
    const int R0 = gwid * 16;
    const int lane = threadIdx.x & 63;
    const int al = lane & 15;
    const int ag = lane >> 4;

    f32x4 acc[8];
    #pragma unroll
    for (int c = 0; c < 8; ++c) acc[c] = (f32x4){0.f, 0.f, 0.f, 0.f};

    for (int m = 0; m < 1 + NREL; ++m) {
        const ushort* Arow = (m == 0)
            ? Xb + (size_t)(R0 + al) * FF
            : Zb + ((size_t)(m - 1) * NN + R0 + al) * FF;
        bf16x8 afr[4];
        #pragma unroll
        for (int s = 0; s < 4; ++s)
            afr[s] = *(const bf16x8*)(Arow + s * 32 + ag * 8);

        const ushort* Wm = Wt + (size_t)m * FF * UU;
        #pragma unroll
        for (int c = 0; c < 8; ++c) {
            const bf16x8* bp = (const bf16x8*)(Wm + (c * 16 + al) * FF);
            #pragma unroll
            for (int s = 0; s < 4; ++s) {
                acc[c] = __builtin_amdgcn_mfma_f32_16x16x32_bf16(
                    afr[s], bp[s * 4 + ag], acc[c], 0, 0, 0);
            }
        }
    }

    #pragma unroll
    for (int c = 0; c < 8; ++c) {
        int col = c * 16 + al;
        float b = bias[col];
        #pragma unroll
        for (int q = 0; q < 4; ++q) {
            int row = R0 + ag * 4 + q;
            out[(size_t)row * UU + col] = fmaxf(acc[c][q] + b, 0.f);
        }
    }
}

// ---------------- launch ----------------

extern "C" void kernel_launch(void* const* d_in, const int* in_sizes, int n_in,
                              void* d_out, int out_size, void* d_ws, size_t ws_size,
                              hipStream_t stream) {
    const float* X     = (const float*)d_in[0];
    const int*   esrc  = (const int*)d_in[1];
    const int*   edst  = (const int*)d_in[2];
    const float* ew    = (const float*)d_in[3];
    const float* Wself = (const float*)d_in[4];
    const float* Wrel  = (const float*)d_in[5];
    const float* bias  = (const float*)d_in[6];
    float* out = (float*)d_out;

    // ws layout (all segments 16B-aligned)
    ushort* Zb    = (ushort*)d_ws;               // NKEY*FF bf16 = 102.4 MB
    ushort* Xb    = Zb + (size_t)NKEY * FF;      // NN*FF bf16   = 12.8 MB
    ushort* Wt    = Xb + (size_t)NN * FF;        // 9*FF*UU bf16 = 0.29 MB
    int*    off   = (int*)(Wt + 9 * FF * UU);    // NKEY+1 (padded to 400008)
    int*    cur   = off + 400008;                // NKEY
    int*    bsums = cur + NKEY;                  // NB (padded to 1568)
    int*    gsrc  = bsums + 1568;                // NET
    float*  gw    = (float*)(gsrc + NET);        // NET

    const int gPrep = (NN * FF / 4 + 255) / 256; // 6250
    const int gKey  = (NKEY + 255) / 256;        // 1563
    const int gEdge = (NET + 255) / 256;         // 1875

    hipLaunchKernelGGL(prep_kernel,  dim3(gPrep), dim3(256), 0, stream,
                       X, Wself, Wrel, Xb, Wt, cur);
    hipLaunchKernelGGL(count_kernel, dim3(gEdge), dim3(256), 0, stream, edst, cur);
    hipLaunchKernelGGL(scanA_kernel, dim3(gKey),  dim3(256), 0, stream, cur, off, bsums);
    hipLaunchKernelGGL(scanB_kernel, dim3(1),     dim3(256), 0, stream, bsums);
    hipLaunchKernelGGL(scanC_kernel, dim3(gKey),  dim3(256), 0, stream, off, bsums, cur);
    hipLaunchKernelGGL(fill_kernel,  dim3(gEdge), dim3(256), 0, stream,
                       esrc, edst, ew, cur, gsrc, gw);

    hipLaunchKernelGGL(agg_kernel,  dim3(NKEY / 4),      dim3(256), 0, stream,
                       Xb, off, gsrc, gw, Zb);
    hipLaunchKernelGGL(gemm_kernel, dim3((NN / 16 + 3) / 4), dim3(256), 0, stream,
                       Xb, Zb, Wt, bias, out);
}

// Round 7
// 147.647 us; speedup vs baseline: 59.3886x; 2.0642x over previous
//
#include <hip/hip_runtime.h>
#include <hip/hip_bf16.h>

#define NN 50000
#define FF 128
#define UU 128
#define NREL 8
#define NE 60000
#define NKEY (NREL * NN)        // 400000
#define NET (NREL * NE)         // 480000

typedef __attribute__((ext_vector_type(8))) short bf16x8;
typedef __attribute__((ext_vector_type(4))) float f32x4;

// ---------------- prep: X->bf16, W->fragment-layout bf16, head init ----------------
// Wf layout: for (m,c,s), a 1KB block at ((m*8+c)*4+s)*512 ushorts; within it,
// lane (ag*16+al) holds 8 bf16: W_m[k = s*32+ag*8+j][col = c*16+al], j=0..7.
// This makes every B-frag load in gemm one coalesced 1KB dwordx4.

__global__ __launch_bounds__(256) void prep_kernel(
    const float* __restrict__ X, const float* __restrict__ Wself,
    const float* __restrict__ Wrel, ushort* __restrict__ Xb,
    ushort* __restrict__ Wf, int* __restrict__ head)
{
    int i = blockIdx.x * 256 + threadIdx.x;
    if (i < NN * FF / 4) {                      // X -> bf16 (1.6M float4s)
        float4 v = ((const float4*)X)[i];
        union { __hip_bfloat162 h[2]; uint2 u; } p;
        p.h[0] = __float22bfloat162_rn(make_float2(v.x, v.y));
        p.h[1] = __float22bfloat162_rn(make_float2(v.z, v.w));
        ((uint2*)Xb)[i] = p.u;
    }
    if (i < NKEY) head[i] = -1;
    if (i < 9 * FF * UU) {                      // W -> fragment layout
        int m = i >> 14, k = (i >> 7) & 127, col = i & 127;
        int c = col >> 4, al = col & 15;
        int s = k >> 5, ag = (k >> 3) & 3, j = k & 7;
        float v = (m == 0) ? Wself[i] : Wrel[i - FF * UU];
        __hip_bfloat16 h = __float2bfloat16(v);
        Wf[((m * 8 + c) * 4 + s) * 512 + (ag * 16 + al) * 8 + j] = *(ushort*)&h;
    }
}

// ---------------- per-(rel,dst) linked list ----------------

__global__ __launch_bounds__(256) void build_kernel(
    const int* __restrict__ edst, int* __restrict__ head, int* __restrict__ nxt)
{
    int i = blockIdx.x * 256 + threadIdx.x;
    if (i < NET) {
        int key = (i / NE) * NN + edst[i];      // const divisor -> magic mul
        nxt[i] = atomicExch(&head[key], i);
    }
}

// ---------------- pass 1: aggregation, one half-wave (32 lanes) per key --------------
// Zb[key][0:128) = bf16( sum w * X[src] ); zeros if list empty.

__global__ __launch_bounds__(256) void agg_kernel(
    const ushort* __restrict__ Xb, const int* __restrict__ head,
    const int* __restrict__ nxt, const int* __restrict__ esrc,
    const float* __restrict__ ew, ushort* __restrict__ Zb)
{
    const int key = blockIdx.x * 8 + (threadIdx.x >> 5);
    const int l = threadIdx.x & 31;             // lane handles elements 4l..4l+3
    float a0 = 0.f, a1 = 0.f, a2 = 0.f, a3 = 0.f;
    int e = head[key];
    while (e >= 0) {
        int s = esrc[e];
        float w = ew[e];
        int en = nxt[e];
        uint2 x = *(const uint2*)(Xb + (size_t)s * FF + 4 * l);
        a0 = fmaf(__uint_as_float(x.x << 16), w, a0);
        a1 = fmaf(__uint_as_float(x.x & 0xffff0000u), w, a1);
        a2 = fmaf(__uint_as_float(x.y << 16), w, a2);
        a3 = fmaf(__uint_as_float(x.y & 0xffff0000u), w, a3);
        e = en;
    }
    union { __hip_bfloat162 h[2]; uint2 u; } p;
    p.h[0] = __float22bfloat162_rn(make_float2(a0, a1));
    p.h[1] = __float22bfloat162_rn(make_float2(a2, a3));
    *(uint2*)(Zb + (size_t)key * FF + 4 * l) = p.u;
}

// ---------------- pass 2: GEMM, one independent wave per 16 output rows --------------
// No LDS, no barriers. A-frag: lane al -> row R0+al, k group ag; contiguous
// short8. B-frag: one coalesced 1KB load per (c,s) from Wf.
// D: col = c*16+al, row = R0 + ag*4 + q (layout verified rounds 5-6).

__global__ __launch_bounds__(256, 3) void gemm_kernel(
    const ushort* __restrict__ Xb, const ushort* __restrict__ Zb,
    const ushort* __restrict__ Wf, const float* __restrict__ bias,
    float* __restrict__ out)
{
    const int gwid = blockIdx.x * 4 + (threadIdx.x >> 6);
    if (gwid >= NN / 16) return;
    const int R0 = gwid * 16;
    const int lane = threadIdx.x & 63;
    const int al = lane & 15;
    const int ag = lane >> 4;

    f32x4 acc[8];
    #pragma unroll
    for (int c = 0; c < 8; ++c) acc[c] = (f32x4){0.f, 0.f, 0.f, 0.f};

    const bf16x8* Wf8 = (const bf16x8*)Wf;      // 64 bf16x8 units per frag block

    for (int m = 0; m < 1 + NREL; ++m) {
        const ushort* Arow = (m == 0)
            ? Xb + (size_t)(R0 + al) * FF
            : Zb + ((size_t)(m - 1) * NN + R0 + al) * FF;
        bf16x8 afr[4];
        #pragma unroll
        for (int s = 0; s < 4; ++s)
            afr[s] = *(const bf16x8*)(Arow + s * 32 + ag * 8);

        #pragma unroll
        for (int c = 0; c < 8; ++c) {
            #pragma unroll
            for (int s = 0; s < 4; ++s) {
                bf16x8 bfr = Wf8[((m * 8 + c) * 4 + s) * 64 + lane];
                acc[c] = __builtin_amdgcn_mfma_f32_16x16x32_bf16(
                    afr[s], bfr, acc[c], 0, 0, 0);
            }
        }
    }

    #pragma unroll
    for (int c = 0; c < 8; ++c) {
        int col = c * 16 + al;
        float b = bias[col];
        #pragma unroll
        for (int q = 0; q < 4; ++q) {
            int row = R0 + ag * 4 + q;
            out[(size_t)row * UU + col] = fmaxf(acc[c][q] + b, 0.f);
        }
    }
}

// ---------------- launch ----------------

extern "C" void kernel_launch(void* const* d_in, const int* in_sizes, int n_in,
                              void* d_out, int out_size, void* d_ws, size_t ws_size,
                              hipStream_t stream) {
    const float* X     = (const float*)d_in[0];
    const int*   esrc  = (const int*)d_in[1];
    const int*   edst  = (const int*)d_in[2];
    const float* ew    = (const float*)d_in[3];
    const float* Wself = (const float*)d_in[4];
    const float* Wrel  = (const float*)d_in[5];
    const float* bias  = (const float*)d_in[6];
    float* out = (float*)d_out;

    // ws layout (16B-aligned segments), ~119 MB total
    ushort* Zb   = (ushort*)d_ws;               // NKEY*FF bf16 = 102.4 MB
    ushort* Xb   = Zb + (size_t)NKEY * FF;      // NN*FF bf16   = 12.8 MB
    ushort* Wf   = Xb + (size_t)NN * FF;        // 9*FF*UU bf16 = 0.29 MB
    int*    head = (int*)(Wf + 9 * FF * UU);    // NKEY
    int*    nxt  = head + NKEY;                 // NET

    hipLaunchKernelGGL(prep_kernel,  dim3(NN * FF / 4 / 256), dim3(256), 0, stream,
                       X, Wself, Wrel, Xb, Wf, head);
    hipLaunchKernelGGL(build_kernel, dim3((NET + 255) / 256), dim3(256), 0, stream,
                       edst, head, nxt);
    hipLaunchKernelGGL(agg_kernel,   dim3(NKEY / 8), dim3(256), 0, stream,
                       Xb, head, nxt, esrc, ew, Zb);
    hipLaunchKernelGGL(gemm_kernel,  dim3((NN / 16 + 3) / 4), dim3(256), 0, stream,
                       Xb, Zb, Wf, bias, out);
}